// Round 12
// baseline (1765.426 us; speedup 1.0000x reference)
//
#include <hip/hip_runtime.h>
#include <math.h>

constexpr int kN = 170000;
constexpr int kE = 2720000;
constexpr int kFin = 128;
constexpr int kFh = 256;
constexpr int kL = 4;
constexpr int kFout = 40;

typedef __attribute__((ext_vector_type(8))) short bf16x8;
typedef __attribute__((ext_vector_type(4))) float f32x4;

__device__ __forceinline__ float jk_b2f(unsigned short u) {
    unsigned int x = ((unsigned int)u) << 16;
    float f;
    __builtin_memcpy(&f, &x, 4);
    return f;
}
__device__ __forceinline__ unsigned short jk_f2b(float f) {
    unsigned int x;
    __builtin_memcpy(&x, &f, 4);
    unsigned int r = (x + 0x7fffu + ((x >> 16) & 1u)) >> 16;
    return (unsigned short)r;
}

union U4 {
    uint4 v;
    unsigned short s[8];
};
union U2 {
    uint2 v;
    unsigned short s[4];
};

__global__ void jkb_zero_i(int* p, int n) {
    int i = blockIdx.x * blockDim.x + threadIdx.x;
    if (i < n) p[i] = 0;
}
__global__ void jkb_zero_f(float* p, int n) {
    int i = blockIdx.x * blockDim.x + threadIdx.x;
    if (i < n) p[i] = 0.0f;
}

// flag[0] = 1 if edge buffer is int64 (element stride shift), else 0; flag[1]=0 cursor.
__global__ void jkb_detect(const int* eb, int* flag) {
    __shared__ int nz;
    if (threadIdx.x == 0) nz = 0;
    __syncthreads();
    int bad = 0;
    for (int j = 0; j < 4; j++) {
        int idx = threadIdx.x * 4 + j;
        if (eb[2 * idx + 1] != 0) bad = 1;
    }
    if (bad) atomicOr(&nz, 1);
    __syncthreads();
    if (threadIdx.x == 0) {
        flag[0] = nz ? 0 : 1;
        flag[1] = 0;
    }
}

// 4 edges/thread: counts[d]++ and record each edge's bucket rank. kE % 4 == 0.
__global__ void jkb_count(const int* eb, const int* flag, int* counts, int* rank) {
    int e0 = (blockIdx.x * blockDim.x + threadIdx.x) * 4;
    if (e0 >= kE) return;
    int s64 = flag[0];
    int d[4];
    if (s64) {
        int4 c1 = *(const int4*)(eb + 2 * ((size_t)kE + e0));
        int4 c2 = *(const int4*)(eb + 2 * ((size_t)kE + e0) + 4);
        d[0] = c1.x; d[1] = c1.z; d[2] = c2.x; d[3] = c2.z;
    } else {
        int4 c1 = *(const int4*)(eb + (size_t)kE + e0);
        d[0] = c1.x; d[1] = c1.y; d[2] = c1.z; d[3] = c1.w;
    }
    int r[4];
#pragma unroll
    for (int q = 0; q < 4; q++) r[q] = atomicAdd(&counts[d[q]], 1);
    *(int4*)(rank + e0) = make_int4(r[0], r[1], r[2], r[3]);
}

__global__ void jkb_nodeprep(const int* counts, float* dinv, float* invdeg, int* off,
                             int* cursor) {
    int n = blockIdx.x * blockDim.x + threadIdx.x;
    if (n < kN) {
        int c = counts[n];
        float deg = (float)c + 1.0f;
        dinv[n] = rsqrtf(deg);
        invdeg[n] = 1.0f / deg;
        off[n] = atomicAdd(cursor, c);
    }
}

// Atomic-free bucket fill, 4 edges/thread: p = off[d] + rank[e]; 8B scatter (src, w).
__global__ void jkb_fill(const int* eb, const int* flag, const int* rank, const int* off,
                         const float* dinv, int2* csr) {
    int e0 = (blockIdx.x * blockDim.x + threadIdx.x) * 4;
    if (e0 >= kE) return;
    int s64 = flag[0];
    int s[4], d[4];
    if (s64) {
        int4 a1 = *(const int4*)(eb + 2 * (size_t)e0);
        int4 a2 = *(const int4*)(eb + 2 * (size_t)e0 + 4);
        s[0] = a1.x; s[1] = a1.z; s[2] = a2.x; s[3] = a2.z;
        int4 c1 = *(const int4*)(eb + 2 * ((size_t)kE + e0));
        int4 c2 = *(const int4*)(eb + 2 * ((size_t)kE + e0) + 4);
        d[0] = c1.x; d[1] = c1.z; d[2] = c2.x; d[3] = c2.z;
    } else {
        int4 a1 = *(const int4*)(eb + (size_t)e0);
        s[0] = a1.x; s[1] = a1.y; s[2] = a1.z; s[3] = a1.w;
        int4 c1 = *(const int4*)(eb + (size_t)kE + e0);
        d[0] = c1.x; d[1] = c1.y; d[2] = c1.z; d[3] = c1.w;
    }
    int4 rr = *(const int4*)(rank + e0);
    int r[4] = {rr.x, rr.y, rr.z, rr.w};
#pragma unroll
    for (int q = 0; q < 4; q++) {
        int p = off[d[q]] + r[q];
        float w = dinv[s[q]] * dinv[d[q]];
        csr[p] = make_int2(s[q], __float_as_int(w));
    }
}

// Single weight-prep: Wt0 (128 transpose), Wt1..3 (256x256 transposes), Wto (bf16
// transposed Wout slices [l][48 cols][256 k], cols 40..47 zero).
__global__ void jkb_prepw(const float* W_in, const float* W_hid, const float* Wout,
                          unsigned short* Wt0, unsigned short* Wt1, unsigned short* Wto) {
    int idx = blockIdx.x * blockDim.x + threadIdx.x;
    if (idx < 32768) {
        int c = idx >> 7, k = idx & 127;
        Wt0[idx] = jk_f2b(W_in[(size_t)k * kFh + c]);
    } else if (idx < 32768 + 196608) {
        int t2 = idx - 32768;
        int l = t2 >> 16, rem = t2 & 65535;
        int c = rem >> 8, k = rem & 255;
        Wt1[(size_t)l * 65536 + rem] = jk_f2b(W_hid[(size_t)l * 65536 + k * kFh + c]);
    } else if (idx < 32768 + 196608 + 49152) {
        int t2 = idx - 32768 - 196608;
        int l = t2 / (48 * 256), rem = t2 % (48 * 256);
        int col = rem >> 8, k = rem & 255;
        float wv = (col < kFout) ? Wout[(size_t)(l * kFh + k) * kFout + col] : 0.f;
        Wto[(size_t)t2] = jk_f2b(wv);
    }
}

// x f32 [kN][128] -> bf16, 8 elems/thread.
__global__ void jkb_xb(const float* x, unsigned short* xb) {
    int i = blockIdx.x * blockDim.x + threadIdx.x;
    if (i >= kN * kFin / 8) return;
    float4 a = *(const float4*)(x + (size_t)i * 8);
    float4 b = *(const float4*)(x + (size_t)i * 8 + 4);
    U4 o;
    o.s[0] = jk_f2b(a.x); o.s[1] = jk_f2b(a.y); o.s[2] = jk_f2b(a.z); o.s[3] = jk_f2b(a.w);
    o.s[4] = jk_f2b(b.x); o.s[5] = jk_f2b(b.y); o.s[6] = jk_f2b(b.z); o.s[7] = jk_f2b(b.w);
    *(uint4*)(xb + (size_t)i * 8) = o.v;
}

// C[bf16, kN x 256] = A' @ W, W transposed bf16 Wt[256][K].
// MODE 0: A bf16 plain (K=128), epilogue adds bias[col] + accumulates BN stats.
// MODE 1: A bf16 raw h, inline BN scale/shift+ReLU (K=256). ALSO fuses the previous
//   layer's JK-accumulation: z += h_norm @ Wtz (y==0 blocks only). The staged As
//   tiles ARE h_norm, so each wave adds 6 extra MFMA/k-step using its af fragments:
//   wn selects which 2 of its 4 m-tiles it covers for z (8 row-tiles x 3 col-tiles
//   split evenly over 4 waves). FIRSTZ: z = acc + bout[col], else z += acc.
template <int MODE, int FIRSTZ>
__global__ __launch_bounds__(256) void jkb_gemm(const unsigned short* A, const unsigned short* Wt,
                                                unsigned short* C, int K, const float* sc,
                                                const float* sh, const float* bias,
                                                float* stats, const unsigned short* Wtz,
                                                const float* bout, float* z) {
    __shared__ unsigned short As[128][40];
    __shared__ unsigned short Bs[128][40];
    __shared__ float ssc[256], ssh[256];
    __shared__ float csum[128], csq[128];
    int tid = threadIdx.x;
    if (MODE == 1) {
        ssc[tid] = sc[tid];
        ssh[tid] = sh[tid];
    } else {
        ssc[tid] = bias[tid];
        if (tid < 128) { csum[tid] = 0.f; csq[tid] = 0.f; }
    }
    __syncthreads();
    int row0 = blockIdx.x * 128;
    int n0 = blockIdx.y * 128;
    int lane = tid & 63, w = tid >> 6;
    int wm = w >> 1, wn = w & 1;
    int lr = lane & 15, lg = lane >> 4;
    bool doz = (MODE == 1) && (blockIdx.y == 0);

    f32x4 acc[4][4];
#pragma unroll
    for (int i = 0; i < 4; i++)
#pragma unroll
        for (int j = 0; j < 4; j++) acc[i][j] = (f32x4){0.f, 0.f, 0.f, 0.f};
    f32x4 accz[2][3];
#pragma unroll
    for (int i = 0; i < 2; i++)
#pragma unroll
        for (int j = 0; j < 3; j++) accz[i][j] = (f32x4){0.f, 0.f, 0.f, 0.f};

    int sr = tid >> 1;
    int skh = (tid & 1) * 16;

    for (int k0 = 0; k0 < K; k0 += 32) {
        {
            int row = row0 + sr;
            if (MODE == 0) {
                uint4 u0 = make_uint4(0, 0, 0, 0), u1 = make_uint4(0, 0, 0, 0);
                if (row < kN) {
                    const unsigned short* g = A + (size_t)row * K + k0 + skh;
                    u0 = *(const uint4*)g;
                    u1 = *(const uint4*)(g + 8);
                }
                *(uint4*)&As[sr][skh] = u0;
                *(uint4*)&As[sr][skh + 8] = u1;
            } else {
                U4 o0, o1;
                if (row < kN) {
                    U4 u0, u1;
                    const unsigned short* g = A + (size_t)row * K + k0 + skh;
                    u0.v = *(const uint4*)g;
                    u1.v = *(const uint4*)(g + 8);
#pragma unroll
                    for (int j = 0; j < 8; j++) {
                        float v = jk_b2f(u0.s[j]) * ssc[k0 + skh + j] + ssh[k0 + skh + j];
                        o0.s[j] = jk_f2b(v > 0.f ? v : 0.f);
                    }
#pragma unroll
                    for (int j = 0; j < 8; j++) {
                        float v = jk_b2f(u1.s[j]) * ssc[k0 + skh + 8 + j] + ssh[k0 + skh + 8 + j];
                        o1.s[j] = jk_f2b(v > 0.f ? v : 0.f);
                    }
                } else {
#pragma unroll
                    for (int j = 0; j < 8; j++) { o0.s[j] = 0; o1.s[j] = 0; }
                }
                *(uint4*)&As[sr][skh] = o0.v;
                *(uint4*)&As[sr][skh + 8] = o1.v;
            }
        }
        {
            const unsigned short* g = Wt + (size_t)(n0 + sr) * K + k0 + skh;
            *(uint4*)&Bs[sr][skh] = *(const uint4*)g;
            *(uint4*)&Bs[sr][skh + 8] = *(const uint4*)(g + 8);
        }
        __syncthreads();

        bf16x8 af[4], bfr[4];
#pragma unroll
        for (int mi = 0; mi < 4; mi++)
            af[mi] = *(const bf16x8*)&As[wm * 64 + mi * 16 + lr][lg * 8];
#pragma unroll
        for (int ni = 0; ni < 4; ni++)
            bfr[ni] = *(const bf16x8*)&Bs[wn * 64 + ni * 16 + lr][lg * 8];
#pragma unroll
        for (int mi = 0; mi < 4; mi++)
#pragma unroll
            for (int ni = 0; ni < 4; ni++)
                acc[mi][ni] = __builtin_amdgcn_mfma_f32_16x16x32_bf16(af[mi], bfr[ni],
                                                                      acc[mi][ni], 0, 0, 0);
        if (doz) {
            // z-fragments from global (hot 24.5KB slice): tile ni rows = ni*16+lr
            bf16x8 bz[3];
#pragma unroll
            for (int ni = 0; ni < 3; ni++)
                bz[ni] = *(const bf16x8*)(Wtz + ((size_t)(ni * 16 + lr) << 8) + k0 + lg * 8);
#pragma unroll
            for (int mzi = 0; mzi < 2; mzi++) {
#pragma unroll
                for (int ni = 0; ni < 3; ni++)
                    accz[mzi][ni] = __builtin_amdgcn_mfma_f32_16x16x32_bf16(
                        af[wn * 2 + mzi], bz[ni], accz[mzi][ni], 0, 0, 0);
            }
        }
        __syncthreads();
    }

    float ps[4] = {0.f, 0.f, 0.f, 0.f}, pq[4] = {0.f, 0.f, 0.f, 0.f};
#pragma unroll
    for (int mi = 0; mi < 4; mi++) {
#pragma unroll
        for (int j = 0; j < 4; j++) {
            int row = row0 + wm * 64 + mi * 16 + lg * 4 + j;
            if (row < kN) {
#pragma unroll
                for (int ni = 0; ni < 4; ni++) {
                    int col = n0 + wn * 64 + ni * 16 + lr;
                    float v = acc[mi][ni][j];
                    if (MODE == 0) {
                        v += ssc[col];
                        ps[ni] += v;
                        pq[ni] += v * v;
                    }
                    C[(size_t)row * kFh + col] = jk_f2b(v);
                }
            }
        }
    }
    if (MODE == 0) {
#pragma unroll
        for (int ni = 0; ni < 4; ni++) {
            int lc = wn * 64 + ni * 16 + lr;
            atomicAdd(&csum[lc], ps[ni]);
            atomicAdd(&csq[lc], pq[ni]);
        }
        __syncthreads();
        if (tid < 128) {
            atomicAdd(&stats[n0 + tid], csum[tid]);
            atomicAdd(&stats[256 + n0 + tid], csq[tid]);
        }
    }
    if (doz) {
#pragma unroll
        for (int mzi = 0; mzi < 2; mzi++) {
#pragma unroll
            for (int j = 0; j < 4; j++) {
                int row = row0 + wm * 64 + (wn * 2 + mzi) * 16 + lg * 4 + j;
                if (row >= kN) continue;
#pragma unroll
                for (int ni = 0; ni < 3; ni++) {
                    int col = ni * 16 + lr;
                    if (col < kFout) {
                        if (FIRSTZ)
                            z[(size_t)row * kFout + col] = accz[mzi][ni][j] + bout[col];
                        else
                            z[(size_t)row * kFout + col] += accz[mzi][ni][j];
                    }
                }
            }
        }
    }
}

// h[n,:] = sum_e w_e * t[src_e,:] + t[n,:]*invdeg[n] (+ bias). r8-verified structure.
template <int CH, int HASB>
__global__ __launch_bounds__(256) void jkb_agg(const unsigned short* t, const float* bias,
                                               const int* off, const int* cnt, const int2* csr,
                                               const float* invdeg, unsigned short* h) {
    constexpr int PC = CH / 32;
    constexpr int DEPTH = (CH == 128) ? 8 : 4;
    int n = blockIdx.x * 8 + (threadIdx.x >> 5);
    if (n >= kN) return;
    int c0 = (threadIdx.x & 31) * PC;

    float acc[PC];
    {
        float sw = invdeg[n];
        if constexpr (PC == 8) {
            U4 u;
            u.v = *(const uint4*)(t + (size_t)n * CH + c0);
#pragma unroll
            for (int j = 0; j < 8; j++) acc[j] = sw * jk_b2f(u.s[j]);
        } else {
            U2 u;
            u.v = *(const uint2*)(t + (size_t)n * CH + c0);
#pragma unroll
            for (int j = 0; j < 4; j++) acc[j] = sw * jk_b2f(u.s[j]);
        }
    }

    int base = off[n], c = cnt[n];
    for (int i = 0; i < c; i += DEPTH) {
        float w[DEPTH];
        U4 u8[PC == 8 ? DEPTH : 1];
        U2 u4[PC == 4 ? DEPTH : 1];
#pragma unroll
        for (int q = 0; q < DEPTH; q++) {
            int e = i + q;
            bool v = e < c;
            int2 cw = csr[v ? base + e : base];
            w[q] = v ? __int_as_float(cw.y) : 0.0f;
            if constexpr (PC == 8)
                u8[q].v = *(const uint4*)(t + (size_t)cw.x * CH + c0);
            else
                u4[q].v = *(const uint2*)(t + (size_t)cw.x * CH + c0);
        }
#pragma unroll
        for (int q = 0; q < DEPTH; q++) {
            if constexpr (PC == 8) {
#pragma unroll
                for (int j = 0; j < 8; j++) acc[j] += w[q] * jk_b2f(u8[q].s[j]);
            } else {
#pragma unroll
                for (int j = 0; j < 4; j++) acc[j] += w[q] * jk_b2f(u4[q].s[j]);
            }
        }
    }

    if constexpr (PC == 8) {
        U4 o;
#pragma unroll
        for (int j = 0; j < 8; j++)
            o.s[j] = jk_f2b(HASB ? acc[j] + bias[c0 + j] : acc[j]);
        *(uint4*)(h + (size_t)n * CH + c0) = o.v;
    } else {
        U2 o;
#pragma unroll
        for (int j = 0; j < 4; j++)
            o.s[j] = jk_f2b(HASB ? acc[j] + bias[c0 + j] : acc[j]);
        *(uint2*)(h + (size_t)n * CH + c0) = o.v;
    }
}

// Column sums/sumsq of raw h -> stats. (r8-verified)
__global__ __launch_bounds__(256) void jkb_bnstats(const unsigned short* h, float* stats) {
    __shared__ float lsum[256], lsq[256];
    int tid = threadIdx.x;
    lsum[tid] = 0.f;
    lsq[tid] = 0.f;
    __syncthreads();
    int c0 = (tid & 31) * 8;
    int grp = tid >> 5;
    float rs[8] = {}, rq[8] = {};
    for (int n = blockIdx.x * 8 + grp; n < kN; n += gridDim.x * 8) {
        U4 u;
        u.v = *(const uint4*)(h + (size_t)n * kFh + c0);
#pragma unroll
        for (int j = 0; j < 8; j++) {
            float v = jk_b2f(u.s[j]);
            rs[j] += v;
            rq[j] += v * v;
        }
    }
#pragma unroll
    for (int j = 0; j < 8; j++) {
        atomicAdd(&lsum[c0 + j], rs[j]);
        atomicAdd(&lsq[c0 + j], rq[j]);
    }
    __syncthreads();
    atomicAdd(&stats[tid], lsum[tid]);
    atomicAdd(&stats[256 + tid], lsq[tid]);
}

__global__ void jkb_bnfinal(const float* stats, const float* gamma, const float* beta, int layer,
                            float* scale, float* shift) {
    int c = threadIdx.x;
    float mean = stats[c] / (float)kN;
    float var = stats[256 + c] / (float)kN - mean * mean;
    var = var < 0.f ? 0.f : var;
    float sc = gamma[layer * kFh + c] * rsqrtf(var + 1e-5f);
    scale[c] = sc;
    shift[c] = beta[layer * kFh + c] - mean * sc;
}

// LAST-layer zacc: reads RAW h, normalizes+ReLU during staging, adds layer-3
// z-contribution (single bf16 Wout) and fuses log-softmax -> out.
__global__ __launch_bounds__(256) void jkb_zlast(const unsigned short* h, const float* scale,
                                                 const float* shift, const unsigned short* Wto,
                                                 float* z, float* out) {
    __shared__ unsigned short Bs[48][264];
    __shared__ unsigned short As[128][40];
    __shared__ float ssc[256], ssh[256];
    int tid = threadIdx.x;
    for (int f = tid; f < 48 * 256; f += 256) {
        Bs[f >> 8][f & 255] = Wto[f];
    }
    ssc[tid] = scale[tid];
    ssh[tid] = shift[tid];
    __syncthreads();

    int row0 = blockIdx.x * 128;
    int w = tid >> 6, lane = tid & 63;
    int lr = lane & 15, lg = lane >> 4;
    int sr = tid >> 1, skh = (tid & 1) * 16;

    f32x4 acc[2][3];
#pragma unroll
    for (int mi = 0; mi < 2; mi++)
#pragma unroll
        for (int ni = 0; ni < 3; ni++) acc[mi][ni] = (f32x4){0.f, 0.f, 0.f, 0.f};

    for (int k0 = 0; k0 < kFh; k0 += 32) {
        int row = row0 + sr;
        U4 o0, o1;
        if (row < kN) {
            U4 u0, u1;
            const unsigned short* g = h + (size_t)row * kFh + k0 + skh;
            u0.v = *(const uint4*)g;
            u1.v = *(const uint4*)(g + 8);
#pragma unroll
            for (int j = 0; j < 8; j++) {
                float v = jk_b2f(u0.s[j]) * ssc[k0 + skh + j] + ssh[k0 + skh + j];
                o0.s[j] = jk_f2b(v > 0.f ? v : 0.f);
            }
#pragma unroll
            for (int j = 0; j < 8; j++) {
                float v = jk_b2f(u1.s[j]) * ssc[k0 + skh + 8 + j] + ssh[k0 + skh + 8 + j];
                o1.s[j] = jk_f2b(v > 0.f ? v : 0.f);
            }
        } else {
#pragma unroll
            for (int j = 0; j < 8; j++) { o0.s[j] = 0; o1.s[j] = 0; }
        }
        *(uint4*)&As[sr][skh] = o0.v;
        *(uint4*)&As[sr][skh + 8] = o1.v;
        __syncthreads();

        bf16x8 af[2], bh[3];
#pragma unroll
        for (int mi = 0; mi < 2; mi++)
            af[mi] = *(const bf16x8*)&As[w * 32 + mi * 16 + lr][lg * 8];
#pragma unroll
        for (int ni = 0; ni < 3; ni++)
            bh[ni] = *(const bf16x8*)&Bs[ni * 16 + lr][k0 + lg * 8];
#pragma unroll
        for (int mi = 0; mi < 2; mi++)
#pragma unroll
            for (int ni = 0; ni < 3; ni++)
                acc[mi][ni] = __builtin_amdgcn_mfma_f32_16x16x32_bf16(af[mi], bh[ni],
                                                                      acc[mi][ni], 0, 0, 0);
        __syncthreads();
    }

#pragma unroll
    for (int mi = 0; mi < 2; mi++) {
#pragma unroll
        for (int j = 0; j < 4; j++) {
            int row = row0 + w * 32 + mi * 16 + lg * 4 + j;
            if (row >= kN) continue;
            const float* zp = z + (size_t)row * kFout;
            float v0 = zp[lr] + acc[mi][0][j];
            float v1 = zp[16 + lr] + acc[mi][1][j];
            float v2 = (lr < 8) ? (zp[32 + lr] + acc[mi][2][j]) : -1e30f;
            float m = fmaxf(fmaxf(v0, v1), v2);
            m = fmaxf(m, __shfl_xor(m, 1, 64));
            m = fmaxf(m, __shfl_xor(m, 2, 64));
            m = fmaxf(m, __shfl_xor(m, 4, 64));
            m = fmaxf(m, __shfl_xor(m, 8, 64));
            float s = expf(v0 - m) + expf(v1 - m) + ((lr < 8) ? expf(v2 - m) : 0.f);
            s += __shfl_xor(s, 1, 64);
            s += __shfl_xor(s, 2, 64);
            s += __shfl_xor(s, 4, 64);
            s += __shfl_xor(s, 8, 64);
            float ls = m + logf(s);
            float* op = out + (size_t)row * kFout;
            op[lr] = v0 - ls;
            op[16 + lr] = v1 - ls;
            if (lr < 8) op[32 + lr] = v2 - ls;
        }
    }
}

extern "C" void kernel_launch(void* const* d_in, const int* in_sizes, int n_in,
                              void* d_out, int out_size, void* d_ws, size_t ws_size,
                              hipStream_t stream) {
    (void)in_sizes; (void)n_in; (void)out_size; (void)ws_size;
    const float* x = (const float*)d_in[0];
    const int* eb = (const int*)d_in[1];
    const float* W_in = (const float*)d_in[2];
    const float* b_in = (const float*)d_in[3];
    const float* W_hid = (const float*)d_in[4];
    const float* b_hid = (const float*)d_in[5];
    const float* gamma = (const float*)d_in[6];
    const float* beta = (const float*)d_in[7];
    const float* W_out = (const float*)d_in[8];
    const float* b_out = (const float*)d_in[9];
    float* out = (float*)d_out;

    char* p = (char*)d_ws;
    auto alloc = [&](size_t b) -> void* {
        void* r = (void*)p;
        p += (b + 255) & ~(size_t)255;
        return r;
    };
    int* flag = (int*)alloc(8);
    int* counts = (int*)alloc((size_t)kN * 4);
    int* off = (int*)alloc((size_t)kN * 4);
    float* dinv = (float*)alloc((size_t)kN * 4);
    float* invdeg = (float*)alloc((size_t)kN * 4);
    float* bnsums = (float*)alloc((size_t)kL * 512 * 4);
    float* bnss = (float*)alloc((size_t)kL * 512 * 4);
    int* rank = (int*)alloc((size_t)kE * 4);
    int2* csr = (int2*)alloc((size_t)kE * 8);
    unsigned short* hA = (unsigned short*)alloc((size_t)kN * kFh * 2);
    unsigned short* hB = (unsigned short*)alloc((size_t)kN * kFh * 2);
    float* z = (float*)alloc((size_t)kN * kFout * 4);
    unsigned short* Wt0 = (unsigned short*)alloc((size_t)kFin * kFh * 2);
    unsigned short* Wt1 = (unsigned short*)alloc((size_t)3 * kFh * kFh * 2);
    unsigned short* Wto = (unsigned short*)alloc((size_t)kL * 48 * 256 * 2);

    jkb_zero_i<<<(kN + 255) / 256, 256, 0, stream>>>(counts, kN);
    jkb_zero_f<<<(kL * 512 + 255) / 256, 256, 0, stream>>>(bnsums, kL * 512);
    jkb_detect<<<1, 256, 0, stream>>>(eb, flag);
    jkb_count<<<(kE / 4 + 255) / 256, 256, 0, stream>>>(eb, flag, counts, rank);
    jkb_nodeprep<<<(kN + 255) / 256, 256, 0, stream>>>(counts, dinv, invdeg, off, flag + 1);
    jkb_fill<<<(kE / 4 + 255) / 256, 256, 0, stream>>>(eb, flag, rank, off, dinv, csr);
    jkb_prepw<<<(32768 + 196608 + 49152 + 255) / 256, 256, 0, stream>>>(W_in, W_hid, W_out,
                                                                        Wt0, Wt1, Wto);
    // layer 0: aggregate-first (Agg(x) @ W == Agg(x @ W)); xb in hB, Agg(x) in hA.
    jkb_xb<<<(kN * kFin / 8 + 255) / 256, 256, 0, stream>>>(x, hB);
    jkb_agg<128, 0><<<(kN + 7) / 8, 256, 0, stream>>>(hB, nullptr, off, counts, csr, invdeg,
                                                      hA);

    unsigned short* Wts[4] = {Wt0, Wt1, Wt1 + 65536, Wt1 + 131072};
    dim3 gg((kN + 127) / 128, 2);
    int zg = (kN + 127) / 128;
    for (int l = 0; l < kL; l++) {
        float* st = bnsums + (size_t)l * 512;
        if (l == 0) {
            jkb_gemm<0, 0><<<gg, 256, 0, stream>>>(hA, Wts[0], hB, kFin, nullptr, nullptr,
                                                   b_in, st, nullptr, nullptr, nullptr);
        } else {
            const float* b = b_hid + (size_t)(l - 1) * kFh;
            float* scp = bnss + (size_t)(l - 1) * 512;
            const unsigned short* wtz = Wto + (size_t)(l - 1) * 48 * 256;
            if (l == 1)
                jkb_gemm<1, 1><<<gg, 256, 0, stream>>>(hB, Wts[l], hA, kFh, scp, scp + 256,
                                                       nullptr, nullptr, wtz, b_out, z);
            else
                jkb_gemm<1, 0><<<gg, 256, 0, stream>>>(hB, Wts[l], hA, kFh, scp, scp + 256,
                                                       nullptr, nullptr, wtz, b_out, z);
            jkb_agg<256, 1><<<(kN + 7) / 8, 256, 0, stream>>>(hA, b, off, counts, csr, invdeg,
                                                              hB);
            jkb_bnstats<<<1024, 256, 0, stream>>>(hB, st);
        }
        jkb_bnfinal<<<1, 256, 0, stream>>>(st, gamma, beta, l, bnss + (size_t)l * 512,
                                           bnss + (size_t)l * 512 + 256);
    }
    // layer-3 z contribution + log-softmax
    jkb_zlast<<<zg, 256, 0, stream>>>(hB, bnss + 3 * 512, bnss + 3 * 512 + 256,
                                      Wto + (size_t)3 * 48 * 256, z, out);
}

// Round 13
// 1559.545 us; speedup vs baseline: 1.1320x; 1.1320x over previous
//
#include <hip/hip_runtime.h>
#include <math.h>

constexpr int kN = 170000;
constexpr int kE = 2720000;
constexpr int kFin = 128;
constexpr int kFh = 256;
constexpr int kL = 4;
constexpr int kFout = 40;

typedef __attribute__((ext_vector_type(8))) short bf16x8;
typedef __attribute__((ext_vector_type(4))) float f32x4;

__device__ __forceinline__ float jk_b2f(unsigned short u) {
    unsigned int x = ((unsigned int)u) << 16;
    float f;
    __builtin_memcpy(&f, &x, 4);
    return f;
}
__device__ __forceinline__ unsigned short jk_f2b(float f) {
    unsigned int x;
    __builtin_memcpy(&x, &f, 4);
    unsigned int r = (x + 0x7fffu + ((x >> 16) & 1u)) >> 16;
    return (unsigned short)r;
}

union U4 {
    uint4 v;
    unsigned short s[8];
};
union U2 {
    uint2 v;
    unsigned short s[4];
};

// Fused init: zero counts, zero bnsums, detect edge dtype (block 0).
__global__ void jkc_init(const int* eb, int* counts, float* bnsums, int* flag) {
    int i = blockIdx.x * blockDim.x + threadIdx.x;
    if (i < kN) counts[i] = 0;
    if (i < kL * 512) bnsums[i] = 0.f;
    if (blockIdx.x == 0) {
        __shared__ int nz;
        if (threadIdx.x == 0) nz = 0;
        __syncthreads();
        int bad = 0;
        for (int j = 0; j < 4; j++) {
            int idx = threadIdx.x * 4 + j;
            if (eb[2 * idx + 1] != 0) bad = 1;
        }
        if (bad) atomicOr(&nz, 1);
        __syncthreads();
        if (threadIdx.x == 0) {
            flag[0] = nz ? 0 : 1;
            flag[1] = 0;
        }
    }
}

// 4 edges/thread: counts[d]++ and record each edge's bucket rank. kE % 4 == 0.
__global__ void jkc_count(const int* eb, const int* flag, int* counts, int* rank) {
    int e0 = (blockIdx.x * blockDim.x + threadIdx.x) * 4;
    if (e0 >= kE) return;
    int s64 = flag[0];
    int d[4];
    if (s64) {
        int4 c1 = *(const int4*)(eb + 2 * ((size_t)kE + e0));
        int4 c2 = *(const int4*)(eb + 2 * ((size_t)kE + e0) + 4);
        d[0] = c1.x; d[1] = c1.z; d[2] = c2.x; d[3] = c2.z;
    } else {
        int4 c1 = *(const int4*)(eb + (size_t)kE + e0);
        d[0] = c1.x; d[1] = c1.y; d[2] = c1.z; d[3] = c1.w;
    }
    int r[4];
#pragma unroll
    for (int q = 0; q < 4; q++) r[q] = atomicAdd(&counts[d[q]], 1);
    *(int4*)(rank + e0) = make_int4(r[0], r[1], r[2], r[3]);
}

__global__ void jkc_nodeprep(const int* counts, float* dinv, float* invdeg, int* off,
                             int* cursor) {
    int n = blockIdx.x * blockDim.x + threadIdx.x;
    if (n < kN) {
        int c = counts[n];
        float deg = (float)c + 1.0f;
        dinv[n] = rsqrtf(deg);
        invdeg[n] = 1.0f / deg;
        off[n] = atomicAdd(cursor, c);
    }
}

// Atomic-free bucket fill, 4 edges/thread: p = off[d] + rank[e]; 8B scatter (src, w).
__global__ void jkc_fill(const int* eb, const int* flag, const int* rank, const int* off,
                         const float* dinv, int2* csr) {
    int e0 = (blockIdx.x * blockDim.x + threadIdx.x) * 4;
    if (e0 >= kE) return;
    int s64 = flag[0];
    int s[4], d[4];
    if (s64) {
        int4 a1 = *(const int4*)(eb + 2 * (size_t)e0);
        int4 a2 = *(const int4*)(eb + 2 * (size_t)e0 + 4);
        s[0] = a1.x; s[1] = a1.z; s[2] = a2.x; s[3] = a2.z;
        int4 c1 = *(const int4*)(eb + 2 * ((size_t)kE + e0));
        int4 c2 = *(const int4*)(eb + 2 * ((size_t)kE + e0) + 4);
        d[0] = c1.x; d[1] = c1.z; d[2] = c2.x; d[3] = c2.z;
    } else {
        int4 a1 = *(const int4*)(eb + (size_t)e0);
        s[0] = a1.x; s[1] = a1.y; s[2] = a1.z; s[3] = a1.w;
        int4 c1 = *(const int4*)(eb + (size_t)kE + e0);
        d[0] = c1.x; d[1] = c1.y; d[2] = c1.z; d[3] = c1.w;
    }
    int4 rr = *(const int4*)(rank + e0);
    int r[4] = {rr.x, rr.y, rr.z, rr.w};
#pragma unroll
    for (int q = 0; q < 4; q++) {
        int p = off[d[q]] + r[q];
        float w = dinv[s[q]] * dinv[d[q]];
        csr[p] = make_int2(s[q], __float_as_int(w));
    }
}

// Single weight-prep: Wt0 (128 transpose), Wt1..3 (256x256 transposes), Wto
// (single-bf16 transposed Wout slices [l][48 cols][256 k], cols 40..47 zero —
// single bf16 verified in r12: absmax unchanged at 0.25).
__global__ void jkc_prepw(const float* W_in, const float* W_hid, const float* Wout,
                          unsigned short* Wt0, unsigned short* Wt1, unsigned short* Wto) {
    int idx = blockIdx.x * blockDim.x + threadIdx.x;
    if (idx < 32768) {
        int c = idx >> 7, k = idx & 127;
        Wt0[idx] = jk_f2b(W_in[(size_t)k * kFh + c]);
    } else if (idx < 32768 + 196608) {
        int t2 = idx - 32768;
        int l = t2 >> 16, rem = t2 & 65535;
        int c = rem >> 8, k = rem & 255;
        Wt1[(size_t)l * 65536 + rem] = jk_f2b(W_hid[(size_t)l * 65536 + k * kFh + c]);
    } else if (idx < 32768 + 196608 + 49152) {
        int t2 = idx - 32768 - 196608;
        int l = t2 / (48 * 256), rem = t2 % (48 * 256);
        int col = rem >> 8, k = rem & 255;
        float wv = (col < kFout) ? Wout[(size_t)(l * kFh + k) * kFout + col] : 0.f;
        Wto[(size_t)t2] = jk_f2b(wv);
    }
}

// x f32 [kN][128] -> bf16, 8 elems/thread.
__global__ void jkc_xb(const float* x, unsigned short* xb) {
    int i = blockIdx.x * blockDim.x + threadIdx.x;
    if (i >= kN * kFin / 8) return;
    float4 a = *(const float4*)(x + (size_t)i * 8);
    float4 b = *(const float4*)(x + (size_t)i * 8 + 4);
    U4 o;
    o.s[0] = jk_f2b(a.x); o.s[1] = jk_f2b(a.y); o.s[2] = jk_f2b(a.z); o.s[3] = jk_f2b(a.w);
    o.s[4] = jk_f2b(b.x); o.s[5] = jk_f2b(b.y); o.s[6] = jk_f2b(b.z); o.s[7] = jk_f2b(b.w);
    *(uint4*)(xb + (size_t)i * 8) = o.v;
}

// C[bf16, kN x 256] = A' @ W, W transposed bf16 Wt[256][K]. (r11-verified)
// MODE 0: A bf16 plain (K=128), epilogue adds bias[col] + accumulates BN stats.
// MODE 1: A bf16 raw h, inline BN scale/shift + ReLU (K=256), no bias/stats.
template <int MODE>
__global__ __launch_bounds__(256) void jkc_gemm(const unsigned short* A, const unsigned short* Wt,
                                                unsigned short* C, int K, const float* sc,
                                                const float* sh, const float* bias,
                                                float* stats) {
    __shared__ unsigned short As[128][40];
    __shared__ unsigned short Bs[128][40];
    __shared__ float ssc[256], ssh[256];
    __shared__ float csum[128], csq[128];
    int tid = threadIdx.x;
    if (MODE == 1) {
        ssc[tid] = sc[tid];
        ssh[tid] = sh[tid];
    } else {
        ssc[tid] = bias[tid];
        if (tid < 128) { csum[tid] = 0.f; csq[tid] = 0.f; }
    }
    __syncthreads();
    int row0 = blockIdx.x * 128;
    int n0 = blockIdx.y * 128;
    int lane = tid & 63, w = tid >> 6;
    int wm = w >> 1, wn = w & 1;
    int lr = lane & 15, lg = lane >> 4;

    f32x4 acc[4][4];
#pragma unroll
    for (int i = 0; i < 4; i++)
#pragma unroll
        for (int j = 0; j < 4; j++) acc[i][j] = (f32x4){0.f, 0.f, 0.f, 0.f};

    int sr = tid >> 1;
    int skh = (tid & 1) * 16;

    for (int k0 = 0; k0 < K; k0 += 32) {
        {
            int row = row0 + sr;
            if (MODE == 0) {
                uint4 u0 = make_uint4(0, 0, 0, 0), u1 = make_uint4(0, 0, 0, 0);
                if (row < kN) {
                    const unsigned short* g = A + (size_t)row * K + k0 + skh;
                    u0 = *(const uint4*)g;
                    u1 = *(const uint4*)(g + 8);
                }
                *(uint4*)&As[sr][skh] = u0;
                *(uint4*)&As[sr][skh + 8] = u1;
            } else {
                U4 o0, o1;
                if (row < kN) {
                    U4 u0, u1;
                    const unsigned short* g = A + (size_t)row * K + k0 + skh;
                    u0.v = *(const uint4*)g;
                    u1.v = *(const uint4*)(g + 8);
#pragma unroll
                    for (int j = 0; j < 8; j++) {
                        float v = jk_b2f(u0.s[j]) * ssc[k0 + skh + j] + ssh[k0 + skh + j];
                        o0.s[j] = jk_f2b(v > 0.f ? v : 0.f);
                    }
#pragma unroll
                    for (int j = 0; j < 8; j++) {
                        float v = jk_b2f(u1.s[j]) * ssc[k0 + skh + 8 + j] + ssh[k0 + skh + 8 + j];
                        o1.s[j] = jk_f2b(v > 0.f ? v : 0.f);
                    }
                } else {
#pragma unroll
                    for (int j = 0; j < 8; j++) { o0.s[j] = 0; o1.s[j] = 0; }
                }
                *(uint4*)&As[sr][skh] = o0.v;
                *(uint4*)&As[sr][skh + 8] = o1.v;
            }
        }
        {
            const unsigned short* g = Wt + (size_t)(n0 + sr) * K + k0 + skh;
            *(uint4*)&Bs[sr][skh] = *(const uint4*)g;
            *(uint4*)&Bs[sr][skh + 8] = *(const uint4*)(g + 8);
        }
        __syncthreads();

        bf16x8 af[4], bfr[4];
#pragma unroll
        for (int mi = 0; mi < 4; mi++)
            af[mi] = *(const bf16x8*)&As[wm * 64 + mi * 16 + lr][lg * 8];
#pragma unroll
        for (int ni = 0; ni < 4; ni++)
            bfr[ni] = *(const bf16x8*)&Bs[wn * 64 + ni * 16 + lr][lg * 8];
#pragma unroll
        for (int mi = 0; mi < 4; mi++)
#pragma unroll
            for (int ni = 0; ni < 4; ni++)
                acc[mi][ni] = __builtin_amdgcn_mfma_f32_16x16x32_bf16(af[mi], bfr[ni],
                                                                      acc[mi][ni], 0, 0, 0);
        __syncthreads();
    }

    float ps[4] = {0.f, 0.f, 0.f, 0.f}, pq[4] = {0.f, 0.f, 0.f, 0.f};
#pragma unroll
    for (int mi = 0; mi < 4; mi++) {
#pragma unroll
        for (int j = 0; j < 4; j++) {
            int row = row0 + wm * 64 + mi * 16 + lg * 4 + j;
            if (row < kN) {
#pragma unroll
                for (int ni = 0; ni < 4; ni++) {
                    int col = n0 + wn * 64 + ni * 16 + lr;
                    float v = acc[mi][ni][j];
                    if (MODE == 0) {
                        v += ssc[col];
                        ps[ni] += v;
                        pq[ni] += v * v;
                    }
                    C[(size_t)row * kFh + col] = jk_f2b(v);
                }
            }
        }
    }
    if (MODE == 0) {
#pragma unroll
        for (int ni = 0; ni < 4; ni++) {
            int lc = wn * 64 + ni * 16 + lr;
            atomicAdd(&csum[lc], ps[ni]);
            atomicAdd(&csq[lc], pq[ni]);
        }
        __syncthreads();
        if (tid < 128) {
            atomicAdd(&stats[n0 + tid], csum[tid]);
            atomicAdd(&stats[256 + n0 + tid], csq[tid]);
        }
    }
}

// h[n,:] = sum_e w_e * t[src_e,:] + t[n,:]*invdeg[n] (+ bias). r8/r11-verified.
template <int CH, int HASB>
__global__ __launch_bounds__(256) void jkc_agg(const unsigned short* t, const float* bias,
                                               const int* off, const int* cnt, const int2* csr,
                                               const float* invdeg, unsigned short* h) {
    constexpr int PC = CH / 32;
    constexpr int DEPTH = (CH == 128) ? 8 : 4;
    int n = blockIdx.x * 8 + (threadIdx.x >> 5);
    if (n >= kN) return;
    int c0 = (threadIdx.x & 31) * PC;

    float acc[PC];
    {
        float sw = invdeg[n];
        if constexpr (PC == 8) {
            U4 u;
            u.v = *(const uint4*)(t + (size_t)n * CH + c0);
#pragma unroll
            for (int j = 0; j < 8; j++) acc[j] = sw * jk_b2f(u.s[j]);
        } else {
            U2 u;
            u.v = *(const uint2*)(t + (size_t)n * CH + c0);
#pragma unroll
            for (int j = 0; j < 4; j++) acc[j] = sw * jk_b2f(u.s[j]);
        }
    }

    int base = off[n], c = cnt[n];
    for (int i = 0; i < c; i += DEPTH) {
        float w[DEPTH];
        U4 u8[PC == 8 ? DEPTH : 1];
        U2 u4[PC == 4 ? DEPTH : 1];
#pragma unroll
        for (int q = 0; q < DEPTH; q++) {
            int e = i + q;
            bool v = e < c;
            int2 cw = csr[v ? base + e : base];
            w[q] = v ? __int_as_float(cw.y) : 0.0f;
            if constexpr (PC == 8)
                u8[q].v = *(const uint4*)(t + (size_t)cw.x * CH + c0);
            else
                u4[q].v = *(const uint2*)(t + (size_t)cw.x * CH + c0);
        }
#pragma unroll
        for (int q = 0; q < DEPTH; q++) {
            if constexpr (PC == 8) {
#pragma unroll
                for (int j = 0; j < 8; j++) acc[j] += w[q] * jk_b2f(u8[q].s[j]);
            } else {
#pragma unroll
                for (int j = 0; j < 4; j++) acc[j] += w[q] * jk_b2f(u4[q].s[j]);
            }
        }
    }

    if constexpr (PC == 8) {
        U4 o;
#pragma unroll
        for (int j = 0; j < 8; j++)
            o.s[j] = jk_f2b(HASB ? acc[j] + bias[c0 + j] : acc[j]);
        *(uint4*)(h + (size_t)n * CH + c0) = o.v;
    } else {
        U2 o;
#pragma unroll
        for (int j = 0; j < 4; j++)
            o.s[j] = jk_f2b(HASB ? acc[j] + bias[c0 + j] : acc[j]);
        *(uint2*)(h + (size_t)n * CH + c0) = o.v;
    }
}

// Column sums/sumsq of raw h -> stats. (r8-verified)
__global__ __launch_bounds__(256) void jkc_bnstats(const unsigned short* h, float* stats) {
    __shared__ float lsum[256], lsq[256];
    int tid = threadIdx.x;
    lsum[tid] = 0.f;
    lsq[tid] = 0.f;
    __syncthreads();
    int c0 = (tid & 31) * 8;
    int grp = tid >> 5;
    float rs[8] = {}, rq[8] = {};
    for (int n = blockIdx.x * 8 + grp; n < kN; n += gridDim.x * 8) {
        U4 u;
        u.v = *(const uint4*)(h + (size_t)n * kFh + c0);
#pragma unroll
        for (int j = 0; j < 8; j++) {
            float v = jk_b2f(u.s[j]);
            rs[j] += v;
            rq[j] += v * v;
        }
    }
#pragma unroll
    for (int j = 0; j < 8; j++) {
        atomicAdd(&lsum[c0 + j], rs[j]);
        atomicAdd(&lsq[c0 + j], rq[j]);
    }
    __syncthreads();
    atomicAdd(&stats[tid], lsum[tid]);
    atomicAdd(&stats[256 + tid], lsq[tid]);
}

__global__ void jkc_bnfinal(const float* stats, const float* gamma, const float* beta, int layer,
                            float* scale, float* shift) {
    int c = threadIdx.x;
    float mean = stats[c] / (float)kN;
    float var = stats[256 + c] / (float)kN - mean * mean;
    var = var < 0.f ? 0.f : var;
    float sc = gamma[layer * kFh + c] * rsqrtf(var + 1e-5f);
    scale[c] = sc;
    shift[c] = beta[layer * kFh + c] - mean * sc;
}

// zacc: reads RAW h, normalizes+ReLU during staging (no write-back),
// z (+)= h_norm @ WoutSlice (SINGLE bf16 — r12-verified accuracy).
// LDS ~38KB -> 4 blocks/CU (vs 2 with hi/lo). LAST fuses log-softmax -> out.
template <int FIRST, int LAST>
__global__ __launch_bounds__(256) void jkc_zacc(const unsigned short* h, const float* scale,
                                                const float* shift, const unsigned short* Wto,
                                                const float* bout, float* z, float* out) {
    __shared__ unsigned short Bs[48][264];
    __shared__ unsigned short As[128][40];
    __shared__ float ssc[256], ssh[256];
    int tid = threadIdx.x;
    for (int f = tid; f < 48 * 256; f += 256) {
        Bs[f >> 8][f & 255] = Wto[f];
    }
    ssc[tid] = scale[tid];
    ssh[tid] = shift[tid];
    __syncthreads();

    int row0 = blockIdx.x * 128;
    int w = tid >> 6, lane = tid & 63;
    int lr = lane & 15, lg = lane >> 4;
    int sr = tid >> 1, skh = (tid & 1) * 16;

    f32x4 acc[2][3];
#pragma unroll
    for (int mi = 0; mi < 2; mi++)
#pragma unroll
        for (int ni = 0; ni < 3; ni++) acc[mi][ni] = (f32x4){0.f, 0.f, 0.f, 0.f};

    for (int k0 = 0; k0 < kFh; k0 += 32) {
        int row = row0 + sr;
        U4 o0, o1;
        if (row < kN) {
            U4 u0, u1;
            const unsigned short* g = h + (size_t)row * kFh + k0 + skh;
            u0.v = *(const uint4*)g;
            u1.v = *(const uint4*)(g + 8);
#pragma unroll
            for (int j = 0; j < 8; j++) {
                float v = jk_b2f(u0.s[j]) * ssc[k0 + skh + j] + ssh[k0 + skh + j];
                o0.s[j] = jk_f2b(v > 0.f ? v : 0.f);
            }
#pragma unroll
            for (int j = 0; j < 8; j++) {
                float v = jk_b2f(u1.s[j]) * ssc[k0 + skh + 8 + j] + ssh[k0 + skh + 8 + j];
                o1.s[j] = jk_f2b(v > 0.f ? v : 0.f);
            }
        } else {
#pragma unroll
            for (int j = 0; j < 8; j++) { o0.s[j] = 0; o1.s[j] = 0; }
        }
        *(uint4*)&As[sr][skh] = o0.v;
        *(uint4*)&As[sr][skh + 8] = o1.v;
        __syncthreads();

        bf16x8 af[2], bh[3];
#pragma unroll
        for (int mi = 0; mi < 2; mi++)
            af[mi] = *(const bf16x8*)&As[w * 32 + mi * 16 + lr][lg * 8];
#pragma unroll
        for (int ni = 0; ni < 3; ni++)
            bh[ni] = *(const bf16x8*)&Bs[ni * 16 + lr][k0 + lg * 8];
#pragma unroll
        for (int mi = 0; mi < 2; mi++)
#pragma unroll
            for (int ni = 0; ni < 3; ni++)
                acc[mi][ni] = __builtin_amdgcn_mfma_f32_16x16x32_bf16(af[mi], bh[ni],
                                                                      acc[mi][ni], 0, 0, 0);
        __syncthreads();
    }

#pragma unroll
    for (int mi = 0; mi < 2; mi++) {
#pragma unroll
        for (int j = 0; j < 4; j++) {
            int row = row0 + w * 32 + mi * 16 + lg * 4 + j;
            if (row >= kN) continue;
            if (!LAST) {
#pragma unroll
                for (int ni = 0; ni < 3; ni++) {
                    int col = ni * 16 + lr;
                    if (col < kFout) {
                        if (FIRST)
                            z[(size_t)row * kFout + col] = acc[mi][ni][j] + bout[col];
                        else
                            z[(size_t)row * kFout + col] += acc[mi][ni][j];
                    }
                }
            } else {
                const float* zp = z + (size_t)row * kFout;
                float v0 = zp[lr] + acc[mi][0][j];
                float v1 = zp[16 + lr] + acc[mi][1][j];
                float v2 = (lr < 8) ? (zp[32 + lr] + acc[mi][2][j]) : -1e30f;
                float m = fmaxf(fmaxf(v0, v1), v2);
                m = fmaxf(m, __shfl_xor(m, 1, 64));
                m = fmaxf(m, __shfl_xor(m, 2, 64));
                m = fmaxf(m, __shfl_xor(m, 4, 64));
                m = fmaxf(m, __shfl_xor(m, 8, 64));
                float s = expf(v0 - m) + expf(v1 - m) + ((lr < 8) ? expf(v2 - m) : 0.f);
                s += __shfl_xor(s, 1, 64);
                s += __shfl_xor(s, 2, 64);
                s += __shfl_xor(s, 4, 64);
                s += __shfl_xor(s, 8, 64);
                float ls = m + logf(s);
                float* op = out + (size_t)row * kFout;
                op[lr] = v0 - ls;
                op[16 + lr] = v1 - ls;
                if (lr < 8) op[32 + lr] = v2 - ls;
            }
        }
    }
}

extern "C" void kernel_launch(void* const* d_in, const int* in_sizes, int n_in,
                              void* d_out, int out_size, void* d_ws, size_t ws_size,
                              hipStream_t stream) {
    (void)in_sizes; (void)n_in; (void)out_size; (void)ws_size;
    const float* x = (const float*)d_in[0];
    const int* eb = (const int*)d_in[1];
    const float* W_in = (const float*)d_in[2];
    const float* b_in = (const float*)d_in[3];
    const float* W_hid = (const float*)d_in[4];
    const float* b_hid = (const float*)d_in[5];
    const float* gamma = (const float*)d_in[6];
    const float* beta = (const float*)d_in[7];
    const float* W_out = (const float*)d_in[8];
    const float* b_out = (const float*)d_in[9];
    float* out = (float*)d_out;

    char* p = (char*)d_ws;
    auto alloc = [&](size_t b) -> void* {
        void* r = (void*)p;
        p += (b + 255) & ~(size_t)255;
        return r;
    };
    int* flag = (int*)alloc(8);
    int* counts = (int*)alloc((size_t)kN * 4);
    int* off = (int*)alloc((size_t)kN * 4);
    float* dinv = (float*)alloc((size_t)kN * 4);
    float* invdeg = (float*)alloc((size_t)kN * 4);
    float* bnsums = (float*)alloc((size_t)kL * 512 * 4);
    float* bnss = (float*)alloc((size_t)kL * 512 * 4);
    int* rank = (int*)alloc((size_t)kE * 4);
    int2* csr = (int2*)alloc((size_t)kE * 8);
    unsigned short* hA = (unsigned short*)alloc((size_t)kN * kFh * 2);
    unsigned short* hB = (unsigned short*)alloc((size_t)kN * kFh * 2);
    float* z = (float*)alloc((size_t)kN * kFout * 4);
    unsigned short* Wt0 = (unsigned short*)alloc((size_t)kFin * kFh * 2);
    unsigned short* Wt1 = (unsigned short*)alloc((size_t)3 * kFh * kFh * 2);
    unsigned short* Wto = (unsigned short*)alloc((size_t)kL * 48 * 256 * 2);

    jkc_init<<<(kN + 255) / 256, 256, 0, stream>>>(eb, counts, bnsums, flag);
    jkc_count<<<(kE / 4 + 255) / 256, 256, 0, stream>>>(eb, flag, counts, rank);
    jkc_nodeprep<<<(kN + 255) / 256, 256, 0, stream>>>(counts, dinv, invdeg, off, flag + 1);
    jkc_fill<<<(kE / 4 + 255) / 256, 256, 0, stream>>>(eb, flag, rank, off, dinv, csr);
    jkc_prepw<<<(32768 + 196608 + 49152 + 255) / 256, 256, 0, stream>>>(W_in, W_hid, W_out,
                                                                        Wt0, Wt1, Wto);
    // layer 0: aggregate-first (Agg(x) @ W == Agg(x @ W)); xb in hB, Agg(x) in hA.
    jkc_xb<<<(kN * kFin / 8 + 255) / 256, 256, 0, stream>>>(x, hB);
    jkc_agg<128, 0><<<(kN + 7) / 8, 256, 0, stream>>>(hB, nullptr, off, counts, csr, invdeg,
                                                      hA);

    unsigned short* Wts[4] = {Wt0, Wt1, Wt1 + 65536, Wt1 + 131072};
    dim3 gg((kN + 127) / 128, 2);
    int zg = (kN + 127) / 128;
    for (int l = 0; l < kL; l++) {
        float* st = bnsums + (size_t)l * 512;
        if (l == 0) {
            jkc_gemm<0><<<gg, 256, 0, stream>>>(hA, Wts[0], hB, kFin, nullptr, nullptr, b_in,
                                                st);
        } else {
            const float* b = b_hid + (size_t)(l - 1) * kFh;
            float* scp = bnss + (size_t)(l - 1) * 512;
            jkc_gemm<1><<<gg, 256, 0, stream>>>(hB, Wts[l], hA, kFh, scp, scp + 256, nullptr,
                                                nullptr);
            jkc_agg<256, 1><<<(kN + 7) / 8, 256, 0, stream>>>(hA, b, off, counts, csr, invdeg,
                                                              hB);
            jkc_bnstats<<<1024, 256, 0, stream>>>(hB, st);
        }
        jkc_bnfinal<<<1, 256, 0, stream>>>(st, gamma, beta, l, bnss + (size_t)l * 512,
                                           bnss + (size_t)l * 512 + 256);
        const unsigned short* wtl = Wto + (size_t)l * 48 * 256;
        float* sc = bnss + (size_t)l * 512;
        if (l == 0)
            jkc_zacc<1, 0><<<zg, 256, 0, stream>>>(hB, sc, sc + 256, wtl, b_out, z, out);
        else if (l < kL - 1)
            jkc_zacc<0, 0><<<zg, 256, 0, stream>>>(hB, sc, sc + 256, wtl, b_out, z, out);
        else
            jkc_zacc<0, 1><<<zg, 256, 0, stream>>>(hB, sc, sc + 256, wtl, b_out, z, out);
    }
}

// Round 14
// 1548.112 us; speedup vs baseline: 1.1404x; 1.0074x over previous
//
#include <hip/hip_runtime.h>
#include <math.h>

constexpr int kN = 170000;
constexpr int kE = 2720000;
constexpr int kFin = 128;
constexpr int kFh = 256;
constexpr int kL = 4;
constexpr int kFout = 40;

typedef __attribute__((ext_vector_type(8))) short bf16x8;
typedef __attribute__((ext_vector_type(4))) float f32x4;

__device__ __forceinline__ float jk_b2f(unsigned short u) {
    unsigned int x = ((unsigned int)u) << 16;
    float f;
    __builtin_memcpy(&f, &x, 4);
    return f;
}
__device__ __forceinline__ unsigned short jk_f2b(float f) {
    unsigned int x;
    __builtin_memcpy(&x, &f, 4);
    unsigned int r = (x + 0x7fffu + ((x >> 16) & 1u)) >> 16;
    return (unsigned short)r;
}

union U4 {
    uint4 v;
    unsigned short s[8];
};
union U2 {
    uint2 v;
    unsigned short s[4];
};

// Fused init: zero counts, zero bnsums, detect edge dtype (block 0).
__global__ void jkd_init(const int* eb, int* counts, float* bnsums, int* flag) {
    int i = blockIdx.x * blockDim.x + threadIdx.x;
    if (i < kN) counts[i] = 0;
    if (i < kL * 512) bnsums[i] = 0.f;
    if (blockIdx.x == 0) {
        __shared__ int nz;
        if (threadIdx.x == 0) nz = 0;
        __syncthreads();
        int bad = 0;
        for (int j = 0; j < 4; j++) {
            int idx = threadIdx.x * 4 + j;
            if (eb[2 * idx + 1] != 0) bad = 1;
        }
        if (bad) atomicOr(&nz, 1);
        __syncthreads();
        if (threadIdx.x == 0) {
            flag[0] = nz ? 0 : 1;
            flag[1] = 0;
        }
    }
}

// 4 edges/thread: counts[d]++ and record each edge's bucket rank. kE % 4 == 0.
__global__ void jkd_count(const int* eb, const int* flag, int* counts, int* rank) {
    int e0 = (blockIdx.x * blockDim.x + threadIdx.x) * 4;
    if (e0 >= kE) return;
    int s64 = flag[0];
    int d[4];
    if (s64) {
        int4 c1 = *(const int4*)(eb + 2 * ((size_t)kE + e0));
        int4 c2 = *(const int4*)(eb + 2 * ((size_t)kE + e0) + 4);
        d[0] = c1.x; d[1] = c1.z; d[2] = c2.x; d[3] = c2.z;
    } else {
        int4 c1 = *(const int4*)(eb + (size_t)kE + e0);
        d[0] = c1.x; d[1] = c1.y; d[2] = c1.z; d[3] = c1.w;
    }
    int r[4];
#pragma unroll
    for (int q = 0; q < 4; q++) r[q] = atomicAdd(&counts[d[q]], 1);
    *(int4*)(rank + e0) = make_int4(r[0], r[1], r[2], r[3]);
}

// Block prefix-scan of counts -> off; ONE cursor atomic per block (was 170K to one
// address = serialized L2 atomics ~1 per cycle, est ~85us hidden below top-5 cutoff).
__global__ __launch_bounds__(256) void jkd_nodeprep(const int* counts, float* dinv,
                                                    float* invdeg, int* off, int* cursor) {
    __shared__ int s[256];
    __shared__ int sbase;
    int tid = threadIdx.x;
    int n = blockIdx.x * 256 + tid;
    int c = (n < kN) ? counts[n] : 0;
    s[tid] = c;
    __syncthreads();
#pragma unroll
    for (int d = 1; d < 256; d <<= 1) {
        int v = (tid >= d) ? s[tid - d] : 0;
        __syncthreads();
        s[tid] += v;
        __syncthreads();
    }
    if (tid == 255) sbase = atomicAdd(cursor, s[255]);
    __syncthreads();
    if (n < kN) {
        off[n] = sbase + s[tid] - c;
        float deg = (float)c + 1.0f;
        dinv[n] = rsqrtf(deg);
        invdeg[n] = 1.0f / deg;
    }
}

// Atomic-free bucket fill, 4 edges/thread: p = off[d] + rank[e]; 8B scatter (src, w).
__global__ void jkd_fill(const int* eb, const int* flag, const int* rank, const int* off,
                         const float* dinv, int2* csr) {
    int e0 = (blockIdx.x * blockDim.x + threadIdx.x) * 4;
    if (e0 >= kE) return;
    int s64 = flag[0];
    int s[4], d[4];
    if (s64) {
        int4 a1 = *(const int4*)(eb + 2 * (size_t)e0);
        int4 a2 = *(const int4*)(eb + 2 * (size_t)e0 + 4);
        s[0] = a1.x; s[1] = a1.z; s[2] = a2.x; s[3] = a2.z;
        int4 c1 = *(const int4*)(eb + 2 * ((size_t)kE + e0));
        int4 c2 = *(const int4*)(eb + 2 * ((size_t)kE + e0) + 4);
        d[0] = c1.x; d[1] = c1.z; d[2] = c2.x; d[3] = c2.z;
    } else {
        int4 a1 = *(const int4*)(eb + (size_t)e0);
        s[0] = a1.x; s[1] = a1.y; s[2] = a1.z; s[3] = a1.w;
        int4 c1 = *(const int4*)(eb + (size_t)kE + e0);
        d[0] = c1.x; d[1] = c1.y; d[2] = c1.z; d[3] = c1.w;
    }
    int4 rr = *(const int4*)(rank + e0);
    int r[4] = {rr.x, rr.y, rr.z, rr.w};
#pragma unroll
    for (int q = 0; q < 4; q++) {
        int p = off[d[q]] + r[q];
        float w = dinv[s[q]] * dinv[d[q]];
        csr[p] = make_int2(s[q], __float_as_int(w));
    }
}

// Single weight-prep: Wt0 (128 transpose), Wt1..3 (256x256 transposes), Wto
// (single-bf16 transposed Wout slices — r12/r13-verified accuracy).
__global__ void jkd_prepw(const float* W_in, const float* W_hid, const float* Wout,
                          unsigned short* Wt0, unsigned short* Wt1, unsigned short* Wto) {
    int idx = blockIdx.x * blockDim.x + threadIdx.x;
    if (idx < 32768) {
        int c = idx >> 7, k = idx & 127;
        Wt0[idx] = jk_f2b(W_in[(size_t)k * kFh + c]);
    } else if (idx < 32768 + 196608) {
        int t2 = idx - 32768;
        int l = t2 >> 16, rem = t2 & 65535;
        int c = rem >> 8, k = rem & 255;
        Wt1[(size_t)l * 65536 + rem] = jk_f2b(W_hid[(size_t)l * 65536 + k * kFh + c]);
    } else if (idx < 32768 + 196608 + 49152) {
        int t2 = idx - 32768 - 196608;
        int l = t2 / (48 * 256), rem = t2 % (48 * 256);
        int col = rem >> 8, k = rem & 255;
        float wv = (col < kFout) ? Wout[(size_t)(l * kFh + k) * kFout + col] : 0.f;
        Wto[(size_t)t2] = jk_f2b(wv);
    }
}

// x f32 [kN][128] -> bf16, 8 elems/thread.
__global__ void jkd_xb(const float* x, unsigned short* xb) {
    int i = blockIdx.x * blockDim.x + threadIdx.x;
    if (i >= kN * kFin / 8) return;
    float4 a = *(const float4*)(x + (size_t)i * 8);
    float4 b = *(const float4*)(x + (size_t)i * 8 + 4);
    U4 o;
    o.s[0] = jk_f2b(a.x); o.s[1] = jk_f2b(a.y); o.s[2] = jk_f2b(a.z); o.s[3] = jk_f2b(a.w);
    o.s[4] = jk_f2b(b.x); o.s[5] = jk_f2b(b.y); o.s[6] = jk_f2b(b.z); o.s[7] = jk_f2b(b.w);
    *(uint4*)(xb + (size_t)i * 8) = o.v;
}

// C[bf16, kN x 256] = A' @ W, W transposed bf16 Wt[256][K]. (r11/r13-verified)
// MODE 0: A bf16 plain (K=128), epilogue adds bias[col] + accumulates BN stats.
// MODE 1: A bf16 raw h, inline BN scale/shift + ReLU (K=256), no bias/stats.
template <int MODE>
__global__ __launch_bounds__(256) void jkd_gemm(const unsigned short* A, const unsigned short* Wt,
                                                unsigned short* C, int K, const float* sc,
                                                const float* sh, const float* bias,
                                                float* stats) {
    __shared__ unsigned short As[128][40];
    __shared__ unsigned short Bs[128][40];
    __shared__ float ssc[256], ssh[256];
    __shared__ float csum[128], csq[128];
    int tid = threadIdx.x;
    if (MODE == 1) {
        ssc[tid] = sc[tid];
        ssh[tid] = sh[tid];
    } else {
        ssc[tid] = bias[tid];
        if (tid < 128) { csum[tid] = 0.f; csq[tid] = 0.f; }
    }
    __syncthreads();
    int row0 = blockIdx.x * 128;
    int n0 = blockIdx.y * 128;
    int lane = tid & 63, w = tid >> 6;
    int wm = w >> 1, wn = w & 1;
    int lr = lane & 15, lg = lane >> 4;

    f32x4 acc[4][4];
#pragma unroll
    for (int i = 0; i < 4; i++)
#pragma unroll
        for (int j = 0; j < 4; j++) acc[i][j] = (f32x4){0.f, 0.f, 0.f, 0.f};

    int sr = tid >> 1;
    int skh = (tid & 1) * 16;

    for (int k0 = 0; k0 < K; k0 += 32) {
        {
            int row = row0 + sr;
            if (MODE == 0) {
                uint4 u0 = make_uint4(0, 0, 0, 0), u1 = make_uint4(0, 0, 0, 0);
                if (row < kN) {
                    const unsigned short* g = A + (size_t)row * K + k0 + skh;
                    u0 = *(const uint4*)g;
                    u1 = *(const uint4*)(g + 8);
                }
                *(uint4*)&As[sr][skh] = u0;
                *(uint4*)&As[sr][skh + 8] = u1;
            } else {
                U4 o0, o1;
                if (row < kN) {
                    U4 u0, u1;
                    const unsigned short* g = A + (size_t)row * K + k0 + skh;
                    u0.v = *(const uint4*)g;
                    u1.v = *(const uint4*)(g + 8);
#pragma unroll
                    for (int j = 0; j < 8; j++) {
                        float v = jk_b2f(u0.s[j]) * ssc[k0 + skh + j] + ssh[k0 + skh + j];
                        o0.s[j] = jk_f2b(v > 0.f ? v : 0.f);
                    }
#pragma unroll
                    for (int j = 0; j < 8; j++) {
                        float v = jk_b2f(u1.s[j]) * ssc[k0 + skh + 8 + j] + ssh[k0 + skh + 8 + j];
                        o1.s[j] = jk_f2b(v > 0.f ? v : 0.f);
                    }
                } else {
#pragma unroll
                    for (int j = 0; j < 8; j++) { o0.s[j] = 0; o1.s[j] = 0; }
                }
                *(uint4*)&As[sr][skh] = o0.v;
                *(uint4*)&As[sr][skh + 8] = o1.v;
            }
        }
        {
            const unsigned short* g = Wt + (size_t)(n0 + sr) * K + k0 + skh;
            *(uint4*)&Bs[sr][skh] = *(const uint4*)g;
            *(uint4*)&Bs[sr][skh + 8] = *(const uint4*)(g + 8);
        }
        __syncthreads();

        bf16x8 af[4], bfr[4];
#pragma unroll
        for (int mi = 0; mi < 4; mi++)
            af[mi] = *(const bf16x8*)&As[wm * 64 + mi * 16 + lr][lg * 8];
#pragma unroll
        for (int ni = 0; ni < 4; ni++)
            bfr[ni] = *(const bf16x8*)&Bs[wn * 64 + ni * 16 + lr][lg * 8];
#pragma unroll
        for (int mi = 0; mi < 4; mi++)
#pragma unroll
            for (int ni = 0; ni < 4; ni++)
                acc[mi][ni] = __builtin_amdgcn_mfma_f32_16x16x32_bf16(af[mi], bfr[ni],
                                                                      acc[mi][ni], 0, 0, 0);
        __syncthreads();
    }

    float ps[4] = {0.f, 0.f, 0.f, 0.f}, pq[4] = {0.f, 0.f, 0.f, 0.f};
#pragma unroll
    for (int mi = 0; mi < 4; mi++) {
#pragma unroll
        for (int j = 0; j < 4; j++) {
            int row = row0 + wm * 64 + mi * 16 + lg * 4 + j;
            if (row < kN) {
#pragma unroll
                for (int ni = 0; ni < 4; ni++) {
                    int col = n0 + wn * 64 + ni * 16 + lr;
                    float v = acc[mi][ni][j];
                    if (MODE == 0) {
                        v += ssc[col];
                        ps[ni] += v;
                        pq[ni] += v * v;
                    }
                    C[(size_t)row * kFh + col] = jk_f2b(v);
                }
            }
        }
    }
    if (MODE == 0) {
#pragma unroll
        for (int ni = 0; ni < 4; ni++) {
            int lc = wn * 64 + ni * 16 + lr;
            atomicAdd(&csum[lc], ps[ni]);
            atomicAdd(&csq[lc], pq[ni]);
        }
        __syncthreads();
        if (tid < 128) {
            atomicAdd(&stats[n0 + tid], csum[tid]);
            atomicAdd(&stats[256 + n0 + tid], csq[tid]);
        }
    }
}

// h[n,:] = sum_e w_e * t[src_e,:] + t[n,:]*invdeg[n] (+ bias).
// r4-verified structure (207us): ONE WAVE PER NODE (no max-degree lockstep waste),
// halves take even/odd edge pairs (depth 2/half = 4 rows in flight), shfl_xor fold.
// CH=256: lane covers 8ch (uint4); CH=128: 4ch (uint2).
template <int CH, int HASB>
__global__ __launch_bounds__(256) void jkd_agg(const unsigned short* t, const float* bias,
                                               const int* off, const int* cnt, const int2* csr,
                                               const float* invdeg, unsigned short* h) {
    constexpr int PC = CH / 32;
    int n = blockIdx.x * 4 + (threadIdx.x >> 6);
    if (n >= kN) return;
    int l = threadIdx.x & 63;
    int half = l >> 5;
    int c0 = (l & 31) * PC;

    float acc[PC];
    {
        float sw = half ? 0.0f : invdeg[n];
        if constexpr (PC == 8) {
            U4 u;
            u.v = *(const uint4*)(t + (size_t)n * CH + c0);
#pragma unroll
            for (int j = 0; j < 8; j++) acc[j] = sw * jk_b2f(u.s[j]);
        } else {
            U2 u;
            u.v = *(const uint2*)(t + (size_t)n * CH + c0);
#pragma unroll
            for (int j = 0; j < 4; j++) acc[j] = sw * jk_b2f(u.s[j]);
        }
    }

    int base = off[n], c = cnt[n];
    for (int i = 0; i < c; i += 4) {
        float w[2];
        U4 u8[PC == 8 ? 2 : 1];
        U2 u4[PC == 4 ? 2 : 1];
#pragma unroll
        for (int q = 0; q < 2; q++) {
            int e = i + half * 2 + q;
            bool v = e < c;
            int2 cw = csr[v ? base + e : base];
            w[q] = v ? __int_as_float(cw.y) : 0.0f;
            if constexpr (PC == 8)
                u8[q].v = *(const uint4*)(t + (size_t)cw.x * CH + c0);
            else
                u4[q].v = *(const uint2*)(t + (size_t)cw.x * CH + c0);
        }
#pragma unroll
        for (int q = 0; q < 2; q++) {
            if constexpr (PC == 8) {
#pragma unroll
                for (int j = 0; j < 8; j++) acc[j] += w[q] * jk_b2f(u8[q].s[j]);
            } else {
#pragma unroll
                for (int j = 0; j < 4; j++) acc[j] += w[q] * jk_b2f(u4[q].s[j]);
            }
        }
    }

#pragma unroll
    for (int j = 0; j < PC; j++) acc[j] += __shfl_xor(acc[j], 32, 64);

    if (half == 0) {
        if constexpr (PC == 8) {
            U4 o;
#pragma unroll
            for (int j = 0; j < 8; j++)
                o.s[j] = jk_f2b(HASB ? acc[j] + bias[c0 + j] : acc[j]);
            *(uint4*)(h + (size_t)n * CH + c0) = o.v;
        } else {
            U2 o;
#pragma unroll
            for (int j = 0; j < 4; j++)
                o.s[j] = jk_f2b(HASB ? acc[j] + bias[c0 + j] : acc[j]);
            *(uint2*)(h + (size_t)n * CH + c0) = o.v;
        }
    }
}

// Column sums/sumsq of raw h -> stats. (r8-verified)
__global__ __launch_bounds__(256) void jkd_bnstats(const unsigned short* h, float* stats) {
    __shared__ float lsum[256], lsq[256];
    int tid = threadIdx.x;
    lsum[tid] = 0.f;
    lsq[tid] = 0.f;
    __syncthreads();
    int c0 = (tid & 31) * 8;
    int grp = tid >> 5;
    float rs[8] = {}, rq[8] = {};
    for (int n = blockIdx.x * 8 + grp; n < kN; n += gridDim.x * 8) {
        U4 u;
        u.v = *(const uint4*)(h + (size_t)n * kFh + c0);
#pragma unroll
        for (int j = 0; j < 8; j++) {
            float v = jk_b2f(u.s[j]);
            rs[j] += v;
            rq[j] += v * v;
        }
    }
#pragma unroll
    for (int j = 0; j < 8; j++) {
        atomicAdd(&lsum[c0 + j], rs[j]);
        atomicAdd(&lsq[c0 + j], rq[j]);
    }
    __syncthreads();
    atomicAdd(&stats[tid], lsum[tid]);
    atomicAdd(&stats[256 + tid], lsq[tid]);
}

__global__ void jkd_bnfinal(const float* stats, const float* gamma, const float* beta, int layer,
                            float* scale, float* shift) {
    int c = threadIdx.x;
    float mean = stats[c] / (float)kN;
    float var = stats[256 + c] / (float)kN - mean * mean;
    var = var < 0.f ? 0.f : var;
    float sc = gamma[layer * kFh + c] * rsqrtf(var + 1e-5f);
    scale[c] = sc;
    shift[c] = beta[layer * kFh + c] - mean * sc;
}

// zacc: reads RAW h, normalizes+ReLU during staging (no write-back),
// z (+)= h_norm @ WoutSlice (single bf16). LAST fuses log-softmax -> out.
template <int FIRST, int LAST>
__global__ __launch_bounds__(256) void jkd_zacc(const unsigned short* h, const float* scale,
                                                const float* shift, const unsigned short* Wto,
                                                const float* bout, float* z, float* out) {
    __shared__ unsigned short Bs[48][264];
    __shared__ unsigned short As[128][40];
    __shared__ float ssc[256], ssh[256];
    int tid = threadIdx.x;
    for (int f = tid; f < 48 * 256; f += 256) {
        Bs[f >> 8][f & 255] = Wto[f];
    }
    ssc[tid] = scale[tid];
    ssh[tid] = shift[tid];
    __syncthreads();

    int row0 = blockIdx.x * 128;
    int w = tid >> 6, lane = tid & 63;
    int lr = lane & 15, lg = lane >> 4;
    int sr = tid >> 1, skh = (tid & 1) * 16;

    f32x4 acc[2][3];
#pragma unroll
    for (int mi = 0; mi < 2; mi++)
#pragma unroll
        for (int ni = 0; ni < 3; ni++) acc[mi][ni] = (f32x4){0.f, 0.f, 0.f, 0.f};

    for (int k0 = 0; k0 < kFh; k0 += 32) {
        int row = row0 + sr;
        U4 o0, o1;
        if (row < kN) {
            U4 u0, u1;
            const unsigned short* g = h + (size_t)row * kFh + k0 + skh;
            u0.v = *(const uint4*)g;
            u1.v = *(const uint4*)(g + 8);
#pragma unroll
            for (int j = 0; j < 8; j++) {
                float v = jk_b2f(u0.s[j]) * ssc[k0 + skh + j] + ssh[k0 + skh + j];
                o0.s[j] = jk_f2b(v > 0.f ? v : 0.f);
            }
#pragma unroll
            for (int j = 0; j < 8; j++) {
                float v = jk_b2f(u1.s[j]) * ssc[k0 + skh + 8 + j] + ssh[k0 + skh + 8 + j];
                o1.s[j] = jk_f2b(v > 0.f ? v : 0.f);
            }
        } else {
#pragma unroll
            for (int j = 0; j < 8; j++) { o0.s[j] = 0; o1.s[j] = 0; }
        }
        *(uint4*)&As[sr][skh] = o0.v;
        *(uint4*)&As[sr][skh + 8] = o1.v;
        __syncthreads();

        bf16x8 af[2], bh[3];
#pragma unroll
        for (int mi = 0; mi < 2; mi++)
            af[mi] = *(const bf16x8*)&As[w * 32 + mi * 16 + lr][lg * 8];
#pragma unroll
        for (int ni = 0; ni < 3; ni++)
            bh[ni] = *(const bf16x8*)&Bs[ni * 16 + lr][k0 + lg * 8];
#pragma unroll
        for (int mi = 0; mi < 2; mi++)
#pragma unroll
            for (int ni = 0; ni < 3; ni++)
                acc[mi][ni] = __builtin_amdgcn_mfma_f32_16x16x32_bf16(af[mi], bh[ni],
                                                                      acc[mi][ni], 0, 0, 0);
        __syncthreads();
    }

#pragma unroll
    for (int mi = 0; mi < 2; mi++) {
#pragma unroll
        for (int j = 0; j < 4; j++) {
            int row = row0 + w * 32 + mi * 16 + lg * 4 + j;
            if (row >= kN) continue;
            if (!LAST) {
#pragma unroll
                for (int ni = 0; ni < 3; ni++) {
                    int col = ni * 16 + lr;
                    if (col < kFout) {
                        if (FIRST)
                            z[(size_t)row * kFout + col] = acc[mi][ni][j] + bout[col];
                        else
                            z[(size_t)row * kFout + col] += acc[mi][ni][j];
                    }
                }
            } else {
                const float* zp = z + (size_t)row * kFout;
                float v0 = zp[lr] + acc[mi][0][j];
                float v1 = zp[16 + lr] + acc[mi][1][j];
                float v2 = (lr < 8) ? (zp[32 + lr] + acc[mi][2][j]) : -1e30f;
                float m = fmaxf(fmaxf(v0, v1), v2);
                m = fmaxf(m, __shfl_xor(m, 1, 64));
                m = fmaxf(m, __shfl_xor(m, 2, 64));
                m = fmaxf(m, __shfl_xor(m, 4, 64));
                m = fmaxf(m, __shfl_xor(m, 8, 64));
                float s = expf(v0 - m) + expf(v1 - m) + ((lr < 8) ? expf(v2 - m) : 0.f);
                s += __shfl_xor(s, 1, 64);
                s += __shfl_xor(s, 2, 64);
                s += __shfl_xor(s, 4, 64);
                s += __shfl_xor(s, 8, 64);
                float ls = m + logf(s);
                float* op = out + (size_t)row * kFout;
                op[lr] = v0 - ls;
                op[16 + lr] = v1 - ls;
                if (lr < 8) op[32 + lr] = v2 - ls;
            }
        }
    }
}

extern "C" void kernel_launch(void* const* d_in, const int* in_sizes, int n_in,
                              void* d_out, int out_size, void* d_ws, size_t ws_size,
                              hipStream_t stream) {
    (void)in_sizes; (void)n_in; (void)out_size; (void)ws_size;
    const float* x = (const float*)d_in[0];
    const int* eb = (const int*)d_in[1];
    const float* W_in = (const float*)d_in[2];
    const float* b_in = (const float*)d_in[3];
    const float* W_hid = (const float*)d_in[4];
    const float* b_hid = (const float*)d_in[5];
    const float* gamma = (const float*)d_in[6];
    const float* beta = (const float*)d_in[7];
    const float* W_out = (const float*)d_in[8];
    const float* b_out = (const float*)d_in[9];
    float* out = (float*)d_out;

    char* p = (char*)d_ws;
    auto alloc = [&](size_t b) -> void* {
        void* r = (void*)p;
        p += (b + 255) & ~(size_t)255;
        return r;
    };
    int* flag = (int*)alloc(8);
    int* counts = (int*)alloc((size_t)kN * 4);
    int* off = (int*)alloc((size_t)kN * 4);
    float* dinv = (float*)alloc((size_t)kN * 4);
    float* invdeg = (float*)alloc((size_t)kN * 4);
    float* bnsums = (float*)alloc((size_t)kL * 512 * 4);
    float* bnss = (float*)alloc((size_t)kL * 512 * 4);
    int* rank = (int*)alloc((size_t)kE * 4);
    int2* csr = (int2*)alloc((size_t)kE * 8);
    unsigned short* hA = (unsigned short*)alloc((size_t)kN * kFh * 2);
    unsigned short* hB = (unsigned short*)alloc((size_t)kN * kFh * 2);
    float* z = (float*)alloc((size_t)kN * kFout * 4);
    unsigned short* Wt0 = (unsigned short*)alloc((size_t)kFin * kFh * 2);
    unsigned short* Wt1 = (unsigned short*)alloc((size_t)3 * kFh * kFh * 2);
    unsigned short* Wto = (unsigned short*)alloc((size_t)kL * 48 * 256 * 2);

    jkd_init<<<(kN + 255) / 256, 256, 0, stream>>>(eb, counts, bnsums, flag);
    jkd_count<<<(kE / 4 + 255) / 256, 256, 0, stream>>>(eb, flag, counts, rank);
    jkd_nodeprep<<<(kN + 255) / 256, 256, 0, stream>>>(counts, dinv, invdeg, off, flag + 1);
    jkd_fill<<<(kE / 4 + 255) / 256, 256, 0, stream>>>(eb, flag, rank, off, dinv, csr);
    jkd_prepw<<<(32768 + 196608 + 49152 + 255) / 256, 256, 0, stream>>>(W_in, W_hid, W_out,
                                                                        Wt0, Wt1, Wto);
    // layer 0: aggregate-first (Agg(x) @ W == Agg(x @ W)); xb in hB, Agg(x) in hA.
    jkd_xb<<<(kN * kFin / 8 + 255) / 256, 256, 0, stream>>>(x, hB);
    jkd_agg<128, 0><<<(kN + 3) / 4, 256, 0, stream>>>(hB, nullptr, off, counts, csr, invdeg,
                                                      hA);

    unsigned short* Wts[4] = {Wt0, Wt1, Wt1 + 65536, Wt1 + 131072};
    dim3 gg((kN + 127) / 128, 2);
    int zg = (kN + 127) / 128;
    for (int l = 0; l < kL; l++) {
        float* st = bnsums + (size_t)l * 512;
        if (l == 0) {
            jkd_gemm<0><<<gg, 256, 0, stream>>>(hA, Wts[0], hB, kFin, nullptr, nullptr, b_in,
                                                st);
        } else {
            const float* b = b_hid + (size_t)(l - 1) * kFh;
            float* scp = bnss + (size_t)(l - 1) * 512;
            jkd_gemm<1><<<gg, 256, 0, stream>>>(hB, Wts[l], hA, kFh, scp, scp + 256, nullptr,
                                                nullptr);
            jkd_agg<256, 1><<<(kN + 3) / 4, 256, 0, stream>>>(hA, b, off, counts, csr, invdeg,
                                                              hB);
            jkd_bnstats<<<1024, 256, 0, stream>>>(hB, st);
        }
        jkd_bnfinal<<<1, 256, 0, stream>>>(st, gamma, beta, l, bnss + (size_t)l * 512,
                                           bnss + (size_t)l * 512 + 256);
        const unsigned short* wtl = Wto + (size_t)l * 48 * 256;
        float* sc = bnss + (size_t)l * 512;
        if (l == 0)
            jkd_zacc<1, 0><<<zg, 256, 0, stream>>>(hB, sc, sc + 256, wtl, b_out, z, out);
        else if (l < kL - 1)
            jkd_zacc<0, 0><<<zg, 256, 0, stream>>>(hB, sc, sc + 256, wtl, b_out, z, out);
        else
            jkd_zacc<0, 1><<<zg, 256, 0, stream>>>(hB, sc, sc + 256, wtl, b_out, z, out);
    }
}